// Round 1
// baseline (139.256 us; speedup 1.0000x reference)
//
#include <hip/hip_runtime.h>
#include <math.h>

#define D_MODEL 512
#define D_STATE 16
#define NSEQ    2048
#define NBATCH  4
#define EPSF    1e-8f
#define LN_EPSF 1e-5f

// ---------------------------------------------------------------------------
// K1: Bu[b][s][n] = (sum_m x[b,n,m] * W_B[s,m]) * B_bar[s]
// Block: 256 threads = 4 waves; each wave handles 4 rows x 16 states.
// W_B (16x512 f32 = 32KB) staged in LDS with B_bar folded in.
// ---------------------------------------------------------------------------
__global__ __launch_bounds__(256) void k1_bu(const float* __restrict__ x,
                                             const float* __restrict__ A_log,
                                             const float* __restrict__ W_B,
                                             float* __restrict__ Bu) {
    __shared__ float wb[D_STATE][D_MODEL + 4];
    const int tid = threadIdx.x;
    const float dt = 1.0f / (float)NSEQ;
    for (int i = tid; i < D_STATE * D_MODEL; i += 256) {
        int s = i / D_MODEL, m = i - s * D_MODEL;
        float A    = -fminf(fmaxf(expf(A_log[s]), EPSF), 10.0f);
        float Abar = expf(A * dt);
        float Bbar = (fabsf(A) > EPSF) ? (Abar - 1.0f) / (A + EPSF) : dt;
        wb[s][m] = W_B[i] * Bbar;
    }
    __syncthreads();

    const int lane = tid & 63, wave = tid >> 6;
    const int s    = lane & 15;
    const int rloc = (lane >> 4) + (wave << 2);          // 0..15
    const int row  = blockIdx.x * 16 + rloc;             // 0..8191
    const float* xr = x + (size_t)row * D_MODEL;

    float acc = 0.f;
    #pragma unroll 4
    for (int m = 0; m < D_MODEL; m += 4) {
        float4 xv = *(const float4*)(xr + m);
        float4 wv = *(const float4*)(&wb[s][m]);
        acc += xv.x * wv.x + xv.y * wv.y + xv.z * wv.z + xv.w * wv.w;
    }
    int b = row / NSEQ, n = row - b * NSEQ;
    Bu[((size_t)b * D_STATE + s) * NSEQ + n] = acc;
}

// ---------------------------------------------------------------------------
// K2: linear scan h[n] = abar*h[n-1] + Bu[n] over N=2048, one block per (b,s).
// Chunked parallel scan: per-thread 8-elem segment -> (a,b) pair scan across
// 256 threads (shfl within wave, LDS across waves). Clip at write.
// Output layout h[b][n][s].
// ---------------------------------------------------------------------------
__global__ __launch_bounds__(256) void k2_scan(const float* __restrict__ Bu,
                                               const float* __restrict__ A_log,
                                               float* __restrict__ h) {
    __shared__ float buf[NSEQ];
    __shared__ float wpair[8];
    const int bs = blockIdx.x;          // b*16 + s
    const int s  = bs & 15;
    const int b  = bs >> 4;
    const float dt = 1.0f / (float)NSEQ;
    float A    = -fminf(fmaxf(expf(A_log[s]), EPSF), 10.0f);
    float abar = expf(A * dt);

    const int tid = threadIdx.x;
    const float* src = Bu + (size_t)bs * NSEQ;
    for (int i = tid; i < NSEQ; i += 256) buf[i] = src[i];
    __syncthreads();

    const int n0 = tid * 8;
    float hh = 0.f;
    #pragma unroll
    for (int j = 0; j < 8; ++j) hh = abar * hh + buf[n0 + j];

    float a = abar * abar; a = a * a; a = a * a;   // abar^8
    float bseg = hh;

    const int lane = tid & 63, wave = tid >> 6;
    #pragma unroll
    for (int off = 1; off < 64; off <<= 1) {
        float ap = __shfl_up(a, off);
        float bp = __shfl_up(bseg, off);
        if (lane >= off) { bseg = a * bp + bseg; a = a * ap; }
    }
    if (lane == 63) { wpair[wave * 2] = a; wpair[wave * 2 + 1] = bseg; }
    __syncthreads();

    float pb = 0.f;  // state after all previous waves (h_in = 0 initially)
    {
        float pa = 1.f;
        for (int w = 0; w < wave; ++w) {
            float wa = wpair[w * 2], wbv = wpair[w * 2 + 1];
            pb = wa * pb + wbv;
            pa = pa * wa;
        }
    }
    float la = __shfl_up(a, 1), lb = __shfl_up(bseg, 1);
    if (lane == 0) { la = 1.f; lb = 0.f; }
    float hin = la * pb + lb;

    hh = hin;
    float outv[8];
    #pragma unroll
    for (int j = 0; j < 8; ++j) {
        hh = abar * hh + buf[n0 + j];
        outv[j] = fminf(fmaxf(hh, -10.f), 10.f);
    }
    __syncthreads();
    #pragma unroll
    for (int j = 0; j < 8; ++j) buf[n0 + j] = outv[j];
    __syncthreads();

    float* dst = h + (size_t)b * NSEQ * D_STATE + s;
    for (int i = tid; i < NSEQ; i += 256) dst[(size_t)i * D_STATE] = buf[i];
}

// ---------------------------------------------------------------------------
// K3: gate logits = x @ W_gate^T  (M=8192, N=512, K=512), written into d_out.
// 64x64 block tile, Kc=32, 256 threads, 4x4 micro-tile with STRIDED
// row/col mapping (r = tr+16i, c = tc+16j) so LDS b128 reads are <=2-way.
// LDS row stride 36 floats keeps 16B alignment for float4 reads.
// ---------------------------------------------------------------------------
#define BK 32
__global__ __launch_bounds__(256) void k3_gemm(const float* __restrict__ x,
                                               const float* __restrict__ Wg,
                                               float* __restrict__ out) {
    __shared__ float xs[64][36];
    __shared__ float ws[64][36];
    const int tid  = threadIdx.x;
    const int row0 = blockIdx.x * 64;
    const int col0 = blockIdx.y * 64;

    const int lrow = tid >> 2;      // 0..63
    const int lq   = tid & 3;       // 0..3  -> k offsets lq*4 and 16+lq*4
    const int tr   = tid >> 4;      // 0..15
    const int tc   = tid & 15;      // 0..15

    const float* xg = x  + (size_t)(row0 + lrow) * D_MODEL;
    const float* wg = Wg + (size_t)(col0 + lrow) * D_MODEL;

    float acc[4][4] = {};

    for (int kc = 0; kc < D_MODEL; kc += BK) {
        float4 xa = *(const float4*)(xg + kc + lq * 4);
        float4 xb = *(const float4*)(xg + kc + 16 + lq * 4);
        float4 wa = *(const float4*)(wg + kc + lq * 4);
        float4 wbv = *(const float4*)(wg + kc + 16 + lq * 4);
        __syncthreads();
        *(float4*)&xs[lrow][lq * 4]      = xa;
        *(float4*)&xs[lrow][16 + lq * 4] = xb;
        *(float4*)&ws[lrow][lq * 4]      = wa;
        *(float4*)&ws[lrow][16 + lq * 4] = wbv;
        __syncthreads();

        #pragma unroll
        for (int k4 = 0; k4 < BK; k4 += 4) {
            float4 av[4], bv[4];
            #pragma unroll
            for (int i = 0; i < 4; ++i) av[i] = *(const float4*)&xs[tr + 16 * i][k4];
            #pragma unroll
            for (int j = 0; j < 4; ++j) bv[j] = *(const float4*)&ws[tc + 16 * j][k4];
            #pragma unroll
            for (int i = 0; i < 4; ++i)
                #pragma unroll
                for (int j = 0; j < 4; ++j)
                    acc[i][j] += av[i].x * bv[j].x + av[i].y * bv[j].y +
                                 av[i].z * bv[j].z + av[i].w * bv[j].w;
        }
    }

    #pragma unroll
    for (int i = 0; i < 4; ++i)
        #pragma unroll
        for (int j = 0; j < 4; ++j)
            out[(size_t)(row0 + tr + 16 * i) * D_MODEL + col0 + tc + 16 * j] = acc[i][j];
}

// ---------------------------------------------------------------------------
// K4: per-row epilogue. One wave per row (4 rows/block).
// Reads gate logits from d_out, computes y = h@W_C^T + D*x, sigmoid blend,
// LayerNorm, overwrites d_out. Each wave reads its row before writing it.
// ---------------------------------------------------------------------------
__global__ __launch_bounds__(256) void k4_fuse(const float* __restrict__ x,
                                               const float* __restrict__ h,
                                               const float* __restrict__ W_C,
                                               const float* __restrict__ Dvec,
                                               const float* __restrict__ b_gate,
                                               const float* __restrict__ gamma,
                                               const float* __restrict__ beta,
                                               float* out) {
    const int tid  = threadIdx.x;
    const int lane = tid & 63, wave = tid >> 6;
    const size_t row = (size_t)blockIdx.x * 4 + wave;
    const float* xr = x + row * D_MODEL;
    const float* lr = out + row * D_MODEL;   // logits (same buffer, read first)
    const float* hr = h + row * D_STATE;

    float hv[D_STATE];
    #pragma unroll
    for (int s = 0; s < D_STATE; ++s) hv[s] = hr[s];

    float yc[8];
    float sum = 0.f, sumsq = 0.f;
    #pragma unroll
    for (int j = 0; j < 8; ++j) {
        const int k = lane + 64 * j;
        float xv = xr[k];
        float z  = lr[k] + b_gate[k];
        float g  = 1.f / (1.f + expf(-z));
        float y  = Dvec[k] * xv;
        const float4* wc = (const float4*)(W_C + (size_t)k * D_STATE);
        #pragma unroll
        for (int q = 0; q < 4; ++q) {
            float4 w4 = wc[q];
            y += hv[q*4+0] * w4.x + hv[q*4+1] * w4.y + hv[q*4+2] * w4.z + hv[q*4+3] * w4.w;
        }
        float v = g * y + (1.f - g) * xv;
        yc[j] = v;
        sum += v; sumsq += v * v;
    }
    #pragma unroll
    for (int off = 32; off; off >>= 1) {
        sum   += __shfl_xor(sum, off);
        sumsq += __shfl_xor(sumsq, off);
    }
    const float mu   = sum * (1.f / (float)D_MODEL);
    const float var  = sumsq * (1.f / (float)D_MODEL) - mu * mu;
    const float rstd = rsqrtf(var + LN_EPSF);
    #pragma unroll
    for (int j = 0; j < 8; ++j) {
        const int k = lane + 64 * j;
        out[row * D_MODEL + k] = (yc[j] - mu) * rstd * gamma[k] + beta[k];
    }
}

// ---------------------------------------------------------------------------
extern "C" void kernel_launch(void* const* d_in, const int* in_sizes, int n_in,
                              void* d_out, int out_size, void* d_ws, size_t ws_size,
                              hipStream_t stream) {
    const float* x     = (const float*)d_in[0];
    const float* A_log = (const float*)d_in[1];
    const float* W_B   = (const float*)d_in[2];
    const float* W_C   = (const float*)d_in[3];
    const float* Dv    = (const float*)d_in[4];
    const float* Wg    = (const float*)d_in[5];
    const float* bg    = (const float*)d_in[6];
    const float* gamma = (const float*)d_in[7];
    const float* beta  = (const float*)d_in[8];
    float* out = (float*)d_out;

    float* Bu = (float*)d_ws;                                  // 4*16*2048 f32 = 512KB
    float* h  = Bu + (size_t)NBATCH * D_STATE * NSEQ;          // 512KB

    const int rows = NBATCH * NSEQ;                            // 8192

    hipLaunchKernelGGL(k1_bu,   dim3(rows / 16),           dim3(256), 0, stream, x, A_log, W_B, Bu);
    hipLaunchKernelGGL(k2_scan, dim3(NBATCH * D_STATE),    dim3(256), 0, stream, Bu, A_log, h);
    hipLaunchKernelGGL(k3_gemm, dim3(rows / 64, D_MODEL / 64), dim3(256), 0, stream, x, Wg, out);
    hipLaunchKernelGGL(k4_fuse, dim3(rows / 4),            dim3(256), 0, stream,
                       x, h, W_C, Dv, bg, gamma, beta, out);
}

// Round 2
// 72.749 us; speedup vs baseline: 1.9142x; 1.9142x over previous
//
#include <hip/hip_runtime.h>
#include <math.h>
#include <stdint.h>

#define D_MODEL 512
#define D_STATE 16
#define NSEQ    2048
#define NBATCH  4
#define EPSF    1e-8f
#define LN_EPSF 1e-5f

typedef __attribute__((ext_vector_type(8))) short short8;
typedef __attribute__((ext_vector_type(4))) float floatx4;

// ---------------------------------------------------------------------------
// K0: f32 -> bf16 (RNE) conversion, 8 elems/thread.
// ---------------------------------------------------------------------------
__global__ __launch_bounds__(256) void k0_cvt(const float* __restrict__ src,
                                              ushort* __restrict__ dst, int n8) {
    int i = blockIdx.x * 256 + threadIdx.x;
    if (i >= n8) return;
    const float4* s = (const float4*)src + (size_t)i * 2;
    float4 a = s[0], b = s[1];
    float v[8] = {a.x, a.y, a.z, a.w, b.x, b.y, b.z, b.w};
    ushort r[8];
    #pragma unroll
    for (int j = 0; j < 8; ++j) {
        uint32_t u = __float_as_uint(v[j]);
        r[j] = (ushort)((u + 0x7fffu + ((u >> 16) & 1u)) >> 16);
    }
    short8 o;
    #pragma unroll
    for (int j = 0; j < 8; ++j) o[j] = (short)r[j];
    *(short8*)(dst + (size_t)i * 8) = o;
}

// ---------------------------------------------------------------------------
// K1: Bu[b][s][n] = (sum_m x[b,n,m] * W_B[s,m]) * B_bar[s]   (f32 path)
// ---------------------------------------------------------------------------
__global__ __launch_bounds__(256) void k1_bu(const float* __restrict__ x,
                                             const float* __restrict__ A_log,
                                             const float* __restrict__ W_B,
                                             float* __restrict__ Bu) {
    __shared__ float wb[D_STATE][D_MODEL + 4];
    const int tid = threadIdx.x;
    const float dt = 1.0f / (float)NSEQ;
    for (int i = tid; i < D_STATE * D_MODEL; i += 256) {
        int s = i / D_MODEL, m = i - s * D_MODEL;
        float A    = -fminf(fmaxf(expf(A_log[s]), EPSF), 10.0f);
        float Abar = expf(A * dt);
        float Bbar = (fabsf(A) > EPSF) ? (Abar - 1.0f) / (A + EPSF) : dt;
        wb[s][m] = W_B[i] * Bbar;
    }
    __syncthreads();

    const int lane = tid & 63, wave = tid >> 6;
    const int s    = lane & 15;
    const int rloc = (lane >> 4) + (wave << 2);
    const int row  = blockIdx.x * 16 + rloc;
    const float* xr = x + (size_t)row * D_MODEL;

    float acc = 0.f;
    #pragma unroll 4
    for (int m = 0; m < D_MODEL; m += 4) {
        float4 xv = *(const float4*)(xr + m);
        float4 wv = *(const float4*)(&wb[s][m]);
        acc += xv.x * wv.x + xv.y * wv.y + xv.z * wv.z + xv.w * wv.w;
    }
    int b = row / NSEQ, n = row - b * NSEQ;
    Bu[((size_t)b * D_STATE + s) * NSEQ + n] = acc;
}

// ---------------------------------------------------------------------------
// K2: chunked parallel scan h[n] = abar*h[n-1] + Bu[n], one block per (b,s).
// ---------------------------------------------------------------------------
__global__ __launch_bounds__(256) void k2_scan(const float* __restrict__ Bu,
                                               const float* __restrict__ A_log,
                                               float* __restrict__ h) {
    __shared__ float buf[NSEQ];
    __shared__ float wpair[8];
    const int bs = blockIdx.x;
    const int s  = bs & 15;
    const int b  = bs >> 4;
    const float dt = 1.0f / (float)NSEQ;
    float A    = -fminf(fmaxf(expf(A_log[s]), EPSF), 10.0f);
    float abar = expf(A * dt);

    const int tid = threadIdx.x;
    const float* src = Bu + (size_t)bs * NSEQ;
    for (int i = tid; i < NSEQ; i += 256) buf[i] = src[i];
    __syncthreads();

    const int n0 = tid * 8;
    float hh = 0.f;
    #pragma unroll
    for (int j = 0; j < 8; ++j) hh = abar * hh + buf[n0 + j];

    float a = abar * abar; a = a * a; a = a * a;   // abar^8
    float bseg = hh;

    const int lane = tid & 63, wave = tid >> 6;
    #pragma unroll
    for (int off = 1; off < 64; off <<= 1) {
        float ap = __shfl_up(a, off);
        float bp = __shfl_up(bseg, off);
        if (lane >= off) { bseg = a * bp + bseg; a = a * ap; }
    }
    if (lane == 63) { wpair[wave * 2] = a; wpair[wave * 2 + 1] = bseg; }
    __syncthreads();

    float pb = 0.f;
    {
        for (int w = 0; w < wave; ++w) {
            float wa = wpair[w * 2], wbv = wpair[w * 2 + 1];
            pb = wa * pb + wbv;
        }
    }
    float la = __shfl_up(a, 1), lb = __shfl_up(bseg, 1);
    if (lane == 0) { la = 1.f; lb = 0.f; }
    float hin = la * pb + lb;

    hh = hin;
    float outv[8];
    #pragma unroll
    for (int j = 0; j < 8; ++j) {
        hh = abar * hh + buf[n0 + j];
        outv[j] = fminf(fmaxf(hh, -10.f), 10.f);
    }
    __syncthreads();
    #pragma unroll
    for (int j = 0; j < 8; ++j) buf[n0 + j] = outv[j];
    __syncthreads();

    float* dst = h + (size_t)b * NSEQ * D_STATE + s;
    for (int i = tid; i < NSEQ; i += 256) dst[(size_t)i * D_STATE] = buf[i];
}

// ---------------------------------------------------------------------------
// K3: gate logits = x @ W_gate^T via bf16 MFMA 16x16x32.
// Tile 128(M) x 64(N), BK=64, 4 waves (each 64x32 out = 4x2 frags).
// global_load_lds width-16 staging with pre-swizzled source; XOR slot
// swizzle (slot ^= row&7) kills the stride-128B 16-way bank conflict.
// Grid 64 x 8 = 512 blocks (2/CU).
// ---------------------------------------------------------------------------
#define BM 128
#define BN 64
#define BKK 64

__global__ __launch_bounds__(256) void k3_mfma(const ushort* __restrict__ A,
                                               const ushort* __restrict__ B,
                                               float* __restrict__ out) {
    __shared__ ushort As[BM * BKK];   // 16 KB, swizzled
    __shared__ ushort Bs[BN * BKK];   // 8 KB, swizzled
    const int tid  = threadIdx.x;
    const int lane = tid & 63, wave = tid >> 6;
    const int row0 = blockIdx.x * BM;
    const int col0 = blockIdx.y * BN;

    // staging: each issue = 256 thr x 16B = 32 rows x 128B
    const int sr = tid >> 3;          // row within issue (0..31)
    const int ps = tid & 7;           // physical 16B slot (0..7)

    // frag-read geometry
    const int wrm = (wave >> 1) * 64;     // wave M offset
    const int wcn = (wave & 1) * 32;      // wave N offset
    const int fr  = lane & 15;            // frag row/col
    const int kg  = lane >> 4;            // k-group (8 bf16 each)
    // physical slot for logical k-slice s (s*4+kg) with row-XOR swizzle;
    // row&7 == fr&7 (rows step by 16), so slot is i-independent.
    const int slot0 = ((0 + kg) ^ (fr & 7)) * 16;
    const int slot1 = ((4 + kg) ^ (fr & 7)) * 16;

    const char* AsB = (const char*)As;
    const char* BsB = (const char*)Bs;

    floatx4 acc[4][2] = {};

    for (int kc = 0; kc < D_MODEL; kc += BKK) {
        __syncthreads();   // previous iter's reads done before overwrite
        #pragma unroll
        for (int is = 0; is < 4; ++is) {
            int r = is * 32 + sr;
            int g = ps ^ (r & 7);                 // logical k-slot for this phys slot
            const ushort* gsrc = A + (size_t)(row0 + r) * D_MODEL + kc + g * 8;
            __builtin_amdgcn_global_load_lds(
                (const __attribute__((address_space(1))) void*)gsrc,
                (__attribute__((address_space(3))) void*)((char*)As + is * 4096 + tid * 16),
                16, 0, 0);
        }
        #pragma unroll
        for (int is = 0; is < 2; ++is) {
            int r = is * 32 + sr;
            int g = ps ^ (r & 7);
            const ushort* gsrc = B + (size_t)(col0 + r) * D_MODEL + kc + g * 8;
            __builtin_amdgcn_global_load_lds(
                (const __attribute__((address_space(1))) void*)gsrc,
                (__attribute__((address_space(3))) void*)((char*)Bs + is * 4096 + tid * 16),
                16, 0, 0);
        }
        __syncthreads();   // drains vmcnt -> LDS tile ready

        short8 af[4][2], bf[2][2];
        #pragma unroll
        for (int i = 0; i < 4; ++i) {
            af[i][0] = *(const short8*)(AsB + (wrm + i * 16 + fr) * 128 + slot0);
            af[i][1] = *(const short8*)(AsB + (wrm + i * 16 + fr) * 128 + slot1);
        }
        #pragma unroll
        for (int j = 0; j < 2; ++j) {
            bf[j][0] = *(const short8*)(BsB + (wcn + j * 16 + fr) * 128 + slot0);
            bf[j][1] = *(const short8*)(BsB + (wcn + j * 16 + fr) * 128 + slot1);
        }
        #pragma unroll
        for (int i = 0; i < 4; ++i)
            #pragma unroll
            for (int j = 0; j < 2; ++j) {
                acc[i][j] = __builtin_amdgcn_mfma_f32_16x16x32_bf16(af[i][0], bf[j][0], acc[i][j], 0, 0, 0);
                acc[i][j] = __builtin_amdgcn_mfma_f32_16x16x32_bf16(af[i][1], bf[j][1], acc[i][j], 0, 0, 0);
            }
    }

    // C/D layout: col = lane&15, row = (lane>>4)*4 + q   [m89-verified]
    const int cr = kg * 4;
    #pragma unroll
    for (int i = 0; i < 4; ++i)
        #pragma unroll
        for (int j = 0; j < 2; ++j)
            #pragma unroll
            for (int q = 0; q < 4; ++q)
                out[(size_t)(row0 + wrm + i * 16 + cr + q) * D_MODEL
                    + col0 + wcn + j * 16 + fr] = acc[i][j][q];
}

// ---------------------------------------------------------------------------
// K4: per-row epilogue (gate blend + y + LayerNorm), one wave per row.
// ---------------------------------------------------------------------------
__global__ __launch_bounds__(256) void k4_fuse(const float* __restrict__ x,
                                               const float* __restrict__ h,
                                               const float* __restrict__ W_C,
                                               const float* __restrict__ Dvec,
                                               const float* __restrict__ b_gate,
                                               const float* __restrict__ gamma,
                                               const float* __restrict__ beta,
                                               float* out) {
    const int tid  = threadIdx.x;
    const int lane = tid & 63, wave = tid >> 6;
    const size_t row = (size_t)blockIdx.x * 4 + wave;
    const float* xr = x + row * D_MODEL;
    const float* lr = out + row * D_MODEL;
    const float* hr = h + row * D_STATE;

    float hv[D_STATE];
    #pragma unroll
    for (int s = 0; s < D_STATE; ++s) hv[s] = hr[s];

    float yc[8];
    float sum = 0.f, sumsq = 0.f;
    #pragma unroll
    for (int j = 0; j < 8; ++j) {
        const int k = lane + 64 * j;
        float xv = xr[k];
        float z  = lr[k] + b_gate[k];
        float g  = 1.f / (1.f + expf(-z));
        float y  = Dvec[k] * xv;
        const float4* wc = (const float4*)(W_C + (size_t)k * D_STATE);
        #pragma unroll
        for (int q = 0; q < 4; ++q) {
            float4 w4 = wc[q];
            y += hv[q*4+0] * w4.x + hv[q*4+1] * w4.y + hv[q*4+2] * w4.z + hv[q*4+3] * w4.w;
        }
        float v = g * y + (1.f - g) * xv;
        yc[j] = v;
        sum += v; sumsq += v * v;
    }
    #pragma unroll
    for (int off = 32; off; off >>= 1) {
        sum   += __shfl_xor(sum, off);
        sumsq += __shfl_xor(sumsq, off);
    }
    const float mu   = sum * (1.f / (float)D_MODEL);
    const float var  = sumsq * (1.f / (float)D_MODEL) - mu * mu;
    const float rstd = rsqrtf(var + LN_EPSF);
    #pragma unroll
    for (int j = 0; j < 8; ++j) {
        const int k = lane + 64 * j;
        out[row * D_MODEL + k] = (yc[j] - mu) * rstd * gamma[k] + beta[k];
    }
}

// ---------------------------------------------------------------------------
extern "C" void kernel_launch(void* const* d_in, const int* in_sizes, int n_in,
                              void* d_out, int out_size, void* d_ws, size_t ws_size,
                              hipStream_t stream) {
    const float* x     = (const float*)d_in[0];
    const float* A_log = (const float*)d_in[1];
    const float* W_B   = (const float*)d_in[2];
    const float* W_C   = (const float*)d_in[3];
    const float* Dv    = (const float*)d_in[4];
    const float* Wg    = (const float*)d_in[5];
    const float* bg    = (const float*)d_in[6];
    const float* gamma = (const float*)d_in[7];
    const float* beta  = (const float*)d_in[8];
    float* out = (float*)d_out;

    const int rows = NBATCH * NSEQ;                 // 8192

    // workspace layout
    ushort* xb  = (ushort*)d_ws;                    // 8192*512 bf16 = 8.4 MB
    ushort* wgb = xb + (size_t)rows * D_MODEL;      // 512*512 bf16 = 0.5 MB
    float*  Bu  = (float*)(wgb + (size_t)D_MODEL * D_MODEL);   // 512 KB
    float*  h   = Bu + (size_t)NBATCH * D_STATE * NSEQ;        // 512 KB

    hipLaunchKernelGGL(k0_cvt, dim3(rows * D_MODEL / 8 / 256), dim3(256), 0, stream,
                       x, xb, rows * D_MODEL / 8);
    hipLaunchKernelGGL(k0_cvt, dim3(D_MODEL * D_MODEL / 8 / 256), dim3(256), 0, stream,
                       Wg, wgb, D_MODEL * D_MODEL / 8);

    hipLaunchKernelGGL(k1_bu,   dim3(rows / 16),        dim3(256), 0, stream, x, A_log, W_B, Bu);
    hipLaunchKernelGGL(k2_scan, dim3(NBATCH * D_STATE), dim3(256), 0, stream, Bu, A_log, h);
    hipLaunchKernelGGL(k3_mfma, dim3(rows / BM, D_MODEL / BN), dim3(256), 0, stream, xb, wgb, out);
    hipLaunchKernelGGL(k4_fuse, dim3(rows / 4),         dim3(256), 0, stream,
                       x, h, W_C, Dv, bg, gamma, beta, out);
}

// Round 4
// 60.627 us; speedup vs baseline: 2.2969x; 1.1999x over previous
//
#include <hip/hip_runtime.h>
#include <math.h>
#include <stdint.h>

#define D_MODEL 512
#define D_STATE 16
#define NSEQ    2048
#define NBATCH  4
#define EPSF    1e-8f
#define LN_EPSF 1e-5f

typedef __attribute__((ext_vector_type(8))) short short8;
typedef __attribute__((ext_vector_type(4))) float floatx4;

__device__ __forceinline__ ushort f2bf(float f) {
    uint32_t u = __float_as_uint(f);
    return (ushort)((u + 0x7fffu + ((u >> 16) & 1u)) >> 16);
}

// ---------------------------------------------------------------------------
// K0: f32 -> bf16 (RNE), used only for W_gate (0.25M elems).
// ---------------------------------------------------------------------------
__global__ __launch_bounds__(256) void k0_cvt(const float* __restrict__ src,
                                              ushort* __restrict__ dst, int n8) {
    int i = blockIdx.x * 256 + threadIdx.x;
    if (i >= n8) return;
    const float4* s = (const float4*)src + (size_t)i * 2;
    float4 a = s[0], b = s[1];
    float v[8] = {a.x, a.y, a.z, a.w, b.x, b.y, b.z, b.w};
    short8 o;
    #pragma unroll
    for (int j = 0; j < 8; ++j) o[j] = (short)f2bf(v[j]);
    *(short8*)(dst + (size_t)i * 8) = o;
}

// ---------------------------------------------------------------------------
// K1: Bu[b][s][n] = (sum_m x[b,n,m] * W_B[s,m]) * B_bar[s]   (f32)
// ---------------------------------------------------------------------------
__global__ __launch_bounds__(256) void k1_bu(const float* __restrict__ x,
                                             const float* __restrict__ A_log,
                                             const float* __restrict__ W_B,
                                             float* __restrict__ Bu) {
    __shared__ float wb[D_STATE][D_MODEL + 4];
    const int tid = threadIdx.x;
    const float dt = 1.0f / (float)NSEQ;
    for (int i = tid; i < D_STATE * D_MODEL; i += 256) {
        int s = i / D_MODEL, m = i - s * D_MODEL;
        float A    = -fminf(fmaxf(expf(A_log[s]), EPSF), 10.0f);
        float Abar = expf(A * dt);
        float Bbar = (fabsf(A) > EPSF) ? (Abar - 1.0f) / (A + EPSF) : dt;
        wb[s][m] = W_B[i] * Bbar;
    }
    __syncthreads();

    const int lane = tid & 63, wave = tid >> 6;
    const int s    = lane & 15;
    const int rloc = (lane >> 4) + (wave << 2);
    const int row  = blockIdx.x * 16 + rloc;
    const float* xr = x + (size_t)row * D_MODEL;

    float acc = 0.f;
    #pragma unroll 4
    for (int m = 0; m < D_MODEL; m += 4) {
        float4 xv = *(const float4*)(xr + m);
        float4 wv = *(const float4*)(&wb[s][m]);
        acc += xv.x * wv.x + xv.y * wv.y + xv.z * wv.z + xv.w * wv.w;
    }
    int b = row / NSEQ, n = row - b * NSEQ;
    Bu[((size_t)b * D_STATE + s) * NSEQ + n] = acc;
}

// ---------------------------------------------------------------------------
// K2: chunked parallel scan h[n] = abar*h[n-1] + Bu[n], one block per (b,s).
// ---------------------------------------------------------------------------
__global__ __launch_bounds__(256) void k2_scan(const float* __restrict__ Bu,
                                               const float* __restrict__ A_log,
                                               float* __restrict__ h) {
    __shared__ float buf[NSEQ];
    __shared__ float wpair[8];
    const int bs = blockIdx.x;
    const int s  = bs & 15;
    const int b  = bs >> 4;
    const float dt = 1.0f / (float)NSEQ;
    float A    = -fminf(fmaxf(expf(A_log[s]), EPSF), 10.0f);
    float abar = expf(A * dt);

    const int tid = threadIdx.x;
    const float* src = Bu + (size_t)bs * NSEQ;
    for (int i = tid; i < NSEQ; i += 256) buf[i] = src[i];
    __syncthreads();

    const int n0 = tid * 8;
    float hh = 0.f;
    #pragma unroll
    for (int j = 0; j < 8; ++j) hh = abar * hh + buf[n0 + j];

    float a = abar * abar; a = a * a; a = a * a;   // abar^8
    float bseg = hh;

    const int lane = tid & 63, wave = tid >> 6;
    #pragma unroll
    for (int off = 1; off < 64; off <<= 1) {
        float ap = __shfl_up(a, off);
        float bp = __shfl_up(bseg, off);
        if (lane >= off) { bseg = a * bp + bseg; a = a * ap; }
    }
    if (lane == 63) { wpair[wave * 2] = a; wpair[wave * 2 + 1] = bseg; }
    __syncthreads();

    float pb = 0.f;
    for (int w = 0; w < wave; ++w) {
        float wa = wpair[w * 2], wbv = wpair[w * 2 + 1];
        pb = wa * pb + wbv;
    }
    float la = __shfl_up(a, 1), lb = __shfl_up(bseg, 1);
    if (lane == 0) { la = 1.f; lb = 0.f; }
    float hin = la * pb + lb;

    hh = hin;
    float outv[8];
    #pragma unroll
    for (int j = 0; j < 8; ++j) {
        hh = abar * hh + buf[n0 + j];
        outv[j] = fminf(fmaxf(hh, -10.f), 10.f);
    }
    __syncthreads();
    #pragma unroll
    for (int j = 0; j < 8; ++j) buf[n0 + j] = outv[j];
    __syncthreads();

    float* dst = h + (size_t)b * NSEQ * D_STATE + s;
    for (int i = tid; i < NSEQ; i += 256) dst[(size_t)i * D_STATE] = buf[i];
}

// ---------------------------------------------------------------------------
// KC: fused  logits = x@Wg^T (bf16 MFMA)  +  y = h@W_C^T (bf16 MFMA, K=32
// zero-padded)  +  D*x  +  sigmoid gate blend  +  LayerNorm  -> out.
// Block = 32 rows x 512 cols (full rows), 4 waves (each 32x128), grid 256.
// A staged reg-side (f32->bf16 cvt) with XOR slot swizzle; B (Wg bf16
// panels 512x64) via global_load_lds with pre-swizzled source.
// ---------------------------------------------------------------------------
#define CBM 32
__global__ __launch_bounds__(256) void kc_fused(
    const float*  __restrict__ x,     // (8192,512)
    const ushort* __restrict__ Wg,    // bf16 (512,512)
    const float*  __restrict__ h,     // (8192,16)
    const float*  __restrict__ W_C,   // (512,16)
    const float*  __restrict__ Dvec,
    const float*  __restrict__ bg,
    const float*  __restrict__ gamma,
    const float*  __restrict__ beta,
    float* __restrict__ out) {
    __shared__ ushort Asub[CBM * 64];      // 4 KB  (swizzled: slot g^(row&7))
    __shared__ ushort Bsub[512 * 64];      // 64 KB (swizzled)
    __shared__ ushort wcs[512 * 32];       // 32 KB (K=32, slots g^(row&3); g>=2 zero)
    __shared__ ushort hs[CBM * 32];        // 2 KB  (same scheme)
    __shared__ float  red[4][CBM][2];      // 1 KB

    const int tid  = threadIdx.x;
    const int lane = tid & 63, wave = tid >> 6;
    const int r0   = blockIdx.x * CBM;
    const int fr   = lane & 15, kg = lane >> 4;
    const int colw = wave * 128;

    // ---- stage W_C (bf16, K-padded to 32) and h rows ----
    #pragma unroll
    for (int it = 0; it < 8; ++it) {
        int idx = it * 256 + tid;          // row*4 + g
        int row = idx >> 2, g = idx & 3;
        short8 v8 = short8{0,0,0,0,0,0,0,0};
        if (g < 2) {
            const float* src = W_C + (size_t)row * D_STATE + g * 8;
            #pragma unroll
            for (int e = 0; e < 8; ++e) v8[e] = (short)f2bf(src[e]);
        }
        int phys = g ^ (row & 3);
        *(short8*)(wcs + row * 32 + phys * 8) = v8;
    }
    if (tid < 128) {
        int row = tid >> 2, g = tid & 3;
        short8 v8 = short8{0,0,0,0,0,0,0,0};
        if (g < 2) {
            const float* src = h + (size_t)(r0 + row) * D_STATE + g * 8;
            #pragma unroll
            for (int e = 0; e < 8; ++e) v8[e] = (short)f2bf(src[e]);
        }
        int phys = g ^ (row & 3);
        *(short8*)(hs + row * 32 + phys * 8) = v8;
    }

    // ---- gate GEMM ----
    const int sr = tid >> 3;       // staging row 0..31
    const int ps = tid & 7;        // phys 16B slot 0..7
    floatx4 acc[2][8] = {};

    for (int kc = 0; kc < D_MODEL; kc += 64) {
        // A: f32 load (issue before barrier so latency overlaps the wait)
        int ga = ps ^ (sr & 7);
        const float* axp = x + (size_t)(r0 + sr) * D_MODEL + kc + ga * 8;
        float4 a0 = *(const float4*)axp;
        float4 a1 = *(const float4*)(axp + 4);

        __syncthreads();           // prior iter's frag reads done (also covers wcs/hs on iter 0)

        {
            float v[8] = {a0.x,a0.y,a0.z,a0.w,a1.x,a1.y,a1.z,a1.w};
            short8 o;
            #pragma unroll
            for (int e = 0; e < 8; ++e) o[e] = (short)f2bf(v[e]);
            *(short8*)(Asub + sr * 64 + ps * 8) = o;
        }
        #pragma unroll
        for (int is = 0; is < 16; ++is) {
            int r = is * 32 + sr;
            int g = ps ^ (r & 7);
            const ushort* gsrc = Wg + (size_t)r * D_MODEL + kc + g * 8;
            __builtin_amdgcn_global_load_lds(
                (const __attribute__((address_space(1))) void*)gsrc,
                (__attribute__((address_space(3))) void*)((char*)Bsub + is * 4096 + tid * 16),
                16, 0, 0);
        }
        __syncthreads();           // vmcnt+lgkm drained -> tile ready

        short8 af[2][2];
        #pragma unroll
        for (int i = 0; i < 2; ++i) {
            int row = i * 16 + fr;
            af[i][0] = *(const short8*)(Asub + row * 64 + ((kg     ) ^ (row & 7)) * 8);
            af[i][1] = *(const short8*)(Asub + row * 64 + ((4 + kg ) ^ (row & 7)) * 8);
        }
        #pragma unroll
        for (int j = 0; j < 8; ++j) {
            int rb = colw + j * 16 + fr;
            short8 b0 = *(const short8*)(Bsub + (size_t)rb * 64 + ((kg    ) ^ (rb & 7)) * 8);
            short8 b1 = *(const short8*)(Bsub + (size_t)rb * 64 + ((4 + kg) ^ (rb & 7)) * 8);
            acc[0][j] = __builtin_amdgcn_mfma_f32_16x16x32_bf16(af[0][0], b0, acc[0][j], 0, 0, 0);
            acc[0][j] = __builtin_amdgcn_mfma_f32_16x16x32_bf16(af[0][1], b1, acc[0][j], 0, 0, 0);
            acc[1][j] = __builtin_amdgcn_mfma_f32_16x16x32_bf16(af[1][0], b0, acc[1][j], 0, 0, 0);
            acc[1][j] = __builtin_amdgcn_mfma_f32_16x16x32_bf16(af[1][1], b1, acc[1][j], 0, 0, 0);
        }
    }

    // ---- y_ssm = h @ W_C^T  (K=32, zero-padded; same frag layout as acc) ----
    floatx4 yc[2][8] = {};
    short8 ah[2];
    #pragma unroll
    for (int i = 0; i < 2; ++i) {
        int row = i * 16 + fr;
        ah[i] = *(const short8*)(hs + row * 32 + (kg ^ (row & 3)) * 8);
    }
    #pragma unroll
    for (int j = 0; j < 8; ++j) {
        int rb = colw + j * 16 + fr;
        short8 bw = *(const short8*)(wcs + rb * 32 + (kg ^ (rb & 3)) * 8);
        yc[0][j] = __builtin_amdgcn_mfma_f32_16x16x32_bf16(ah[0], bw, yc[0][j], 0, 0, 0);
        yc[1][j] = __builtin_amdgcn_mfma_f32_16x16x32_bf16(ah[1], bw, yc[1][j], 0, 0, 0);
    }

    // ---- epilogue: gate blend + LN ----
    float vsum[2][4] = {}, vsq[2][4] = {};
    #pragma unroll
    for (int j = 0; j < 8; ++j) {
        int col = colw + j * 16 + fr;
        float dv = Dvec[col], bgv = bg[col];
        #pragma unroll
        for (int i = 0; i < 2; ++i) {
            int rloc = i * 16 + kg * 4;
            #pragma unroll
            for (int q = 0; q < 4; ++q) {
                float xv = x[(size_t)(r0 + rloc + q) * D_MODEL + col];
                float lg = acc[i][j][q] + bgv;
                float gt = 1.f / (1.f + expf(-lg));
                float yv = yc[i][j][q] + dv * xv;
                float v  = gt * yv + (1.f - gt) * xv;
                acc[i][j][q] = v;
                vsum[i][q] += v;
                vsq[i][q]  += v * v;
            }
        }
    }
    #pragma unroll
    for (int off = 1; off < 16; off <<= 1) {
        #pragma unroll
        for (int i = 0; i < 2; ++i)
            #pragma unroll
            for (int q = 0; q < 4; ++q) {
                vsum[i][q] += __shfl_xor(vsum[i][q], off);
                vsq[i][q]  += __shfl_xor(vsq[i][q], off);
            }
    }
    if (fr == 0) {
        #pragma unroll
        for (int i = 0; i < 2; ++i)
            #pragma unroll
            for (int q = 0; q < 4; ++q) {
                int rl = i * 16 + kg * 4 + q;
                red[wave][rl][0] = vsum[i][q];
                red[wave][rl][1] = vsq[i][q];
            }
    }
    __syncthreads();
    float mu[2][4], rs[2][4];
    #pragma unroll
    for (int i = 0; i < 2; ++i)
        #pragma unroll
        for (int q = 0; q < 4; ++q) {
            int rl = i * 16 + kg * 4 + q;
            float s = 0.f, ss = 0.f;
            #pragma unroll
            for (int w = 0; w < 4; ++w) { s += red[w][rl][0]; ss += red[w][rl][1]; }
            float m   = s * (1.f / (float)D_MODEL);
            float var = ss * (1.f / (float)D_MODEL) - m * m;
            mu[i][q] = m;
            rs[i][q] = rsqrtf(var + LN_EPSF);
        }
    #pragma unroll
    for (int j = 0; j < 8; ++j) {
        int col = colw + j * 16 + fr;
        float ga = gamma[col], be = beta[col];
        #pragma unroll
        for (int i = 0; i < 2; ++i)
            #pragma unroll
            for (int q = 0; q < 4; ++q)
                out[(size_t)(r0 + i * 16 + kg * 4 + q) * D_MODEL + col] =
                    (acc[i][j][q] - mu[i][q]) * rs[i][q] * ga + be;
    }
}

// ---------------------------------------------------------------------------
extern "C" void kernel_launch(void* const* d_in, const int* in_sizes, int n_in,
                              void* d_out, int out_size, void* d_ws, size_t ws_size,
                              hipStream_t stream) {
    const float* x     = (const float*)d_in[0];
    const float* A_log = (const float*)d_in[1];
    const float* W_B   = (const float*)d_in[2];
    const float* W_C   = (const float*)d_in[3];
    const float* Dv    = (const float*)d_in[4];
    const float* Wg    = (const float*)d_in[5];
    const float* bg    = (const float*)d_in[6];
    const float* gamma = (const float*)d_in[7];
    const float* beta  = (const float*)d_in[8];
    float* out = (float*)d_out;

    const int rows = NBATCH * NSEQ;                       // 8192

    ushort* wgb = (ushort*)d_ws;                          // 512KB bf16 W_gate
    float*  Bu  = (float*)(wgb + (size_t)D_MODEL * D_MODEL);
    float*  h   = Bu + (size_t)NBATCH * D_STATE * NSEQ;

    hipLaunchKernelGGL(k0_cvt, dim3(D_MODEL * D_MODEL / 8 / 256), dim3(256), 0, stream,
                       Wg, wgb, D_MODEL * D_MODEL / 8);
    hipLaunchKernelGGL(k1_bu,   dim3(rows / 16),        dim3(256), 0, stream, x, A_log, W_B, Bu);
    hipLaunchKernelGGL(k2_scan, dim3(NBATCH * D_STATE), dim3(256), 0, stream, Bu, A_log, h);
    hipLaunchKernelGGL(kc_fused, dim3(rows / CBM),      dim3(256), 0, stream,
                       x, wgb, h, W_C, Dv, bg, gamma, beta, out);
}

// Round 5
// 51.973 us; speedup vs baseline: 2.6794x; 1.1665x over previous
//
#include <hip/hip_runtime.h>
#include <math.h>
#include <stdint.h>

#define D_MODEL 512
#define D_STATE 16
#define NSEQ    2048
#define NBATCH  4
#define EPSF    1e-8f
#define LN_EPSF 1e-5f

typedef __attribute__((ext_vector_type(8))) short short8;
typedef __attribute__((ext_vector_type(4))) float floatx4;

__device__ __forceinline__ ushort f2bf(float f) {
    uint32_t u = __float_as_uint(f);
    return (ushort)((u + 0x7fffu + ((u >> 16) & 1u)) >> 16);
}

// ---------------------------------------------------------------------------
// KA: blocks 0..127  -> W_gate f32->bf16 cvt (k0)
//     blocks 128..639 -> Bu = (x @ W_B^T) * B_bar  (k1, f32 VALU)
// ---------------------------------------------------------------------------
__global__ __launch_bounds__(256) void kA(const float* __restrict__ x,
                                          const float* __restrict__ A_log,
                                          const float* __restrict__ W_B,
                                          const float* __restrict__ Wg,
                                          ushort* __restrict__ wgb,
                                          float* __restrict__ Bu) {
    __shared__ float wb[D_STATE][D_MODEL + 4];
    const int tid = threadIdx.x;

    if (blockIdx.x < 128) {               // ---- k0: cvt W_gate ----
        int i = blockIdx.x * 256 + tid;   // 32768 threads x 8 elems
        const float4* s = (const float4*)Wg + (size_t)i * 2;
        float4 a = s[0], b = s[1];
        float v[8] = {a.x, a.y, a.z, a.w, b.x, b.y, b.z, b.w};
        short8 o;
        #pragma unroll
        for (int j = 0; j < 8; ++j) o[j] = (short)f2bf(v[j]);
        *(short8*)(wgb + (size_t)i * 8) = o;
        return;
    }

    // ---- k1 ----
    const float dt = 1.0f / (float)NSEQ;
    for (int i = tid; i < D_STATE * D_MODEL; i += 256) {
        int s = i / D_MODEL, m = i - s * D_MODEL;
        float A    = -fminf(fmaxf(expf(A_log[s]), EPSF), 10.0f);
        float Abar = expf(A * dt);
        float Bbar = (fabsf(A) > EPSF) ? (Abar - 1.0f) / (A + EPSF) : dt;
        wb[s][m] = W_B[i] * Bbar;
    }
    __syncthreads();

    const int lane = tid & 63, wave = tid >> 6;
    const int s    = lane & 15;
    const int rloc = (lane >> 4) + (wave << 2);
    const int row  = (blockIdx.x - 128) * 16 + rloc;
    const float* xr = x + (size_t)row * D_MODEL;

    float acc = 0.f;
    #pragma unroll 4
    for (int m = 0; m < D_MODEL; m += 4) {
        float4 xv = *(const float4*)(xr + m);
        float4 wv = *(const float4*)(&wb[s][m]);
        acc += xv.x * wv.x + xv.y * wv.y + xv.z * wv.z + xv.w * wv.w;
    }
    int b = row / NSEQ, n = row - b * NSEQ;
    Bu[((size_t)b * D_STATE + s) * NSEQ + n] = acc;
}

// ---------------------------------------------------------------------------
// K2: chunked parallel scan; output h_T[bs][n] (contiguous, coalesced).
// ---------------------------------------------------------------------------
__global__ __launch_bounds__(256) void k2_scan(const float* __restrict__ Bu,
                                               const float* __restrict__ A_log,
                                               float* __restrict__ hT) {
    __shared__ float buf[NSEQ];
    __shared__ float wpair[8];
    const int bs = blockIdx.x;
    const int s  = bs & 15;
    const float dt = 1.0f / (float)NSEQ;
    float A    = -fminf(fmaxf(expf(A_log[s]), EPSF), 10.0f);
    float abar = expf(A * dt);

    const int tid = threadIdx.x;
    const float* src = Bu + (size_t)bs * NSEQ;
    for (int i = tid; i < NSEQ; i += 256) buf[i] = src[i];
    __syncthreads();

    const int n0 = tid * 8;
    float hh = 0.f;
    #pragma unroll
    for (int j = 0; j < 8; ++j) hh = abar * hh + buf[n0 + j];

    float a = abar * abar; a = a * a; a = a * a;   // abar^8
    float bseg = hh;

    const int lane = tid & 63, wave = tid >> 6;
    #pragma unroll
    for (int off = 1; off < 64; off <<= 1) {
        float ap = __shfl_up(a, off);
        float bp = __shfl_up(bseg, off);
        if (lane >= off) { bseg = a * bp + bseg; a = a * ap; }
    }
    if (lane == 63) { wpair[wave * 2] = a; wpair[wave * 2 + 1] = bseg; }
    __syncthreads();

    float pb = 0.f;
    for (int w = 0; w < wave; ++w) {
        float wa = wpair[w * 2], wbv = wpair[w * 2 + 1];
        pb = wa * pb + wbv;
    }
    float la = __shfl_up(a, 1), lb = __shfl_up(bseg, 1);
    if (lane == 0) { la = 1.f; lb = 0.f; }
    float hin = la * pb + lb;

    hh = hin;
    float outv[8];
    #pragma unroll
    for (int j = 0; j < 8; ++j) {
        hh = abar * hh + buf[n0 + j];
        outv[j] = fminf(fmaxf(hh, -10.f), 10.f);
    }
    __syncthreads();
    #pragma unroll
    for (int j = 0; j < 8; ++j) buf[n0 + j] = outv[j];
    __syncthreads();

    float* dst = hT + (size_t)bs * NSEQ;
    for (int i = tid; i < NSEQ; i += 256) dst[i] = buf[i];
}

// ---------------------------------------------------------------------------
// KC: fused gate GEMM (bf16 MFMA) + h@W_C^T + blend + LayerNorm.
// CBM=16 rows x 512 cols, BK=32, grid 512 = 2 blocks/CU (TLP to hide the
// per-K-step panel drain). LDS ~50 KB.
// ---------------------------------------------------------------------------
#define CBM 16
#define BKC 32
__global__ __launch_bounds__(256) void kc_fused(
    const float*  __restrict__ x,     // (8192,512)
    const ushort* __restrict__ Wg,    // bf16 (512,512)
    const float*  __restrict__ hT,    // (64,2048)  h transposed
    const float*  __restrict__ W_C,   // (512,16)
    const float*  __restrict__ Dvec,
    const float*  __restrict__ bg,
    const float*  __restrict__ gamma,
    const float*  __restrict__ beta,
    float* __restrict__ out) {
    __shared__ ushort Bsub[512 * BKC];     // 32 KB, rows of 64B, slot^=(row&3)
    __shared__ ushort Asub[CBM * BKC];     // 1 KB, same scheme
    __shared__ ushort wcs[512 * 16];       // 16 KB: 2 slots (k=0..15), slot^=(row&1)
    __shared__ ushort hs[CBM * 16];        // 512 B
    __shared__ float  red[4][CBM][2];      // 512 B

    const int tid  = threadIdx.x;
    const int lane = tid & 63, wave = tid >> 6;
    const int r0   = blockIdx.x * CBM;            // global row base
    const int fr   = lane & 15, kg = lane >> 4;
    const int colw = wave * 128;

    // ---- prologue staging: W_C (bf16) and h-tile (gather from hT) ----
    #pragma unroll
    for (int it = 0; it < 4; ++it) {
        int idx = it * 256 + tid;                 // row*2 + g
        int row = idx >> 1, g = idx & 1;
        const float4* src = (const float4*)(W_C + (size_t)row * D_STATE + g * 8);
        float4 v0 = src[0], v1 = src[1];
        float v[8] = {v0.x,v0.y,v0.z,v0.w,v1.x,v1.y,v1.z,v1.w};
        short8 o;
        #pragma unroll
        for (int e = 0; e < 8; ++e) o[e] = (short)f2bf(v[e]);
        *(short8*)(wcs + row * 16 + (g ^ (row & 1)) * 8) = o;
    }
    {   // h gather: thread t -> (s = t&15, nloc = t>>4)
        int s = tid & 15, nloc = tid >> 4;
        int b = r0 >> 11, n0 = r0 & (NSEQ - 1);
        float hv = hT[((size_t)b * D_STATE + s) * NSEQ + n0 + nloc];
        int g = s >> 3;
        hs[nloc * 16 + (g ^ (nloc & 1)) * 8 + (s & 7)] = f2bf(hv);
    }

    // ---- gate GEMM: 16 K-steps of BK=32 ----
    floatx4 acc[8] = {};
    const int arow = tid >> 4;            // 0..15 (A staging row)
    const int akp  = (tid & 15) * 2;      // k-pair within 32

    for (int kc = 0; kc < D_MODEL; kc += BKC) {
        // A: f32 loads issued before the barrier (latency overlaps wait)
        const float* axp = x + (size_t)(r0 + arow) * D_MODEL + kc + akp;
        float2 av = *(const float2*)axp;

        __syncthreads();                  // prior iter frag-reads done

        {   // A -> LDS (swizzled 16B slots)
            int g = akp >> 3;
            int addr = arow * BKC + ((g ^ (arow & 3)) * 8) + (akp & 7);
            ushort2 o; o.x = f2bf(av.x); o.y = f2bf(av.y);
            *(ushort2*)(Asub + addr) = o;
        }
        #pragma unroll
        for (int is = 0; is < 8; ++is) {  // B panel: 512 rows x 32 k = 32 KB
            int row = is * 64 + (tid >> 2);
            int g   = (tid & 3) ^ (row & 3);
            const ushort* gsrc = Wg + (size_t)row * D_MODEL + kc + g * 8;
            __builtin_amdgcn_global_load_lds(
                (const __attribute__((address_space(1))) void*)gsrc,
                (__attribute__((address_space(3))) void*)((char*)Bsub + is * 4096 + tid * 16),
                16, 0, 0);
        }
        __syncthreads();                  // tile ready

        short8 af = *(const short8*)(Asub + fr * BKC + ((kg ^ (fr & 3)) * 8));
        #pragma unroll
        for (int j = 0; j < 8; ++j) {
            int rb = colw + j * 16 + fr;
            short8 bv = *(const short8*)(Bsub + (size_t)rb * BKC + ((kg ^ (rb & 3)) * 8));
            acc[j] = __builtin_amdgcn_mfma_f32_16x16x32_bf16(af, bv, acc[j], 0, 0, 0);
        }
    }

    // ---- y_ssm = h @ W_C^T (K=32, upper half zero) ----
    const short8 z8 = short8{0,0,0,0,0,0,0,0};
    short8 ah = (kg < 2) ? *(const short8*)(hs + fr * 16 + ((kg ^ (fr & 1)) * 8)) : z8;
    floatx4 yc[8] = {};
    #pragma unroll
    for (int j = 0; j < 8; ++j) {
        int rb = colw + j * 16 + fr;
        short8 bw = (kg < 2) ? *(const short8*)(wcs + rb * 16 + ((kg ^ (rb & 1)) * 8)) : z8;
        yc[j] = __builtin_amdgcn_mfma_f32_16x16x32_bf16(ah, bw, yc[j], 0, 0, 0);
    }

    // ---- epilogue: blend + LN.  lane covers rows kg*4+q, cols colw+j*16+fr
    float vsum[4] = {}, vsq[4] = {};
    #pragma unroll
    for (int j = 0; j < 8; ++j) {
        int col = colw + j * 16 + fr;
        float dv = Dvec[col], bgv = bg[col];
        #pragma unroll
        for (int q = 0; q < 4; ++q) {
            int rl = kg * 4 + q;
            float xv = x[(size_t)(r0 + rl) * D_MODEL + col];
            float lg = acc[j][q] + bgv;
            float gt = 1.f / (1.f + expf(-lg));
            float yv = yc[j][q] + dv * xv;
            float v  = gt * yv + (1.f - gt) * xv;
            acc[j][q] = v;
            vsum[q] += v;
            vsq[q]  += v * v;
        }
    }
    #pragma unroll
    for (int off = 1; off < 16; off <<= 1) {
        #pragma unroll
        for (int q = 0; q < 4; ++q) {
            vsum[q] += __shfl_xor(vsum[q], off);
            vsq[q]  += __shfl_xor(vsq[q], off);
        }
    }
    if (fr == 0) {
        #pragma unroll
        for (int q = 0; q < 4; ++q) {
            red[wave][kg * 4 + q][0] = vsum[q];
            red[wave][kg * 4 + q][1] = vsq[q];
        }
    }
    __syncthreads();
    float mu[4], rs[4];
    #pragma unroll
    for (int q = 0; q < 4; ++q) {
        int rl = kg * 4 + q;
        float s = 0.f, ss = 0.f;
        #pragma unroll
        for (int w = 0; w < 4; ++w) { s += red[w][rl][0]; ss += red[w][rl][1]; }
        float m   = s * (1.f / (float)D_MODEL);
        float var = ss * (1.f / (float)D_MODEL) - m * m;
        mu[q] = m;
        rs[q] = rsqrtf(var + LN_EPSF);
    }
    #pragma unroll
    for (int j = 0; j < 8; ++j) {
        int col = colw + j * 16 + fr;
        float ga = gamma[col], be = beta[col];
        #pragma unroll
        for (int q = 0; q < 4; ++q)
            out[(size_t)(r0 + kg * 4 + q) * D_MODEL + col] =
                (acc[j][q] - mu[q]) * rs[q] * ga + be;
    }
}

// ---------------------------------------------------------------------------
extern "C" void kernel_launch(void* const* d_in, const int* in_sizes, int n_in,
                              void* d_out, int out_size, void* d_ws, size_t ws_size,
                              hipStream_t stream) {
    const float* x     = (const float*)d_in[0];
    const float* A_log = (const float*)d_in[1];
    const float* W_B   = (const float*)d_in[2];
    const float* W_C   = (const float*)d_in[3];
    const float* Dv    = (const float*)d_in[4];
    const float* Wg    = (const float*)d_in[5];
    const float* bg    = (const float*)d_in[6];
    const float* gamma = (const float*)d_in[7];
    const float* beta  = (const float*)d_in[8];
    float* out = (float*)d_out;

    const int rows = NBATCH * NSEQ;                       // 8192

    ushort* wgb = (ushort*)d_ws;                          // 512 KB bf16 W_gate
    float*  Bu  = (float*)(wgb + (size_t)D_MODEL * D_MODEL);
    float*  hT  = Bu + (size_t)NBATCH * D_STATE * NSEQ;

    hipLaunchKernelGGL(kA,      dim3(128 + rows / 16),  dim3(256), 0, stream,
                       x, A_log, W_B, Wg, wgb, Bu);
    hipLaunchKernelGGL(k2_scan, dim3(NBATCH * D_STATE), dim3(256), 0, stream, Bu, A_log, hT);
    hipLaunchKernelGGL(kc_fused, dim3(rows / CBM),      dim3(256), 0, stream,
                       x, wgb, hT, W_C, Dv, bg, gamma, beta, out);
}

// Round 7
// 46.920 us; speedup vs baseline: 2.9679x; 1.1077x over previous
//
#include <hip/hip_runtime.h>
#include <math.h>
#include <stdint.h>

#define D_MODEL 512
#define D_STATE 16
#define NSEQ    2048
#define NBATCH  4
#define EPSF    1e-8f
#define LN_EPSF 1e-5f
#define DT      (1.0f / 2048.0f)

typedef __attribute__((ext_vector_type(8))) short short8;
typedef __attribute__((ext_vector_type(4))) float floatx4;

__device__ __forceinline__ ushort f2bf(float f) {
    uint32_t u = __float_as_uint(f);
    return (ushort)((u + 0x7fffu + ((u >> 16) & 1u)) >> 16);
}

// ---------------------------------------------------------------------------
// kP (512 blocks x 256): per block = 16 rows (= one scan chunk).
//  - W_gate f32->bf16 slice (64 thr)
//  - Bu dot: thread (s=lane&15, rloc=(lane>>4)+wave*4) over LDS-staged W_B*B_bar
//  - 16-row LOCAL scan of h (shfl over lane offsets 16/32 + cross-wave LDS)
//  - writes hL[row][s] (unclipped local) + states[chunk][s] (chunk end)
// ---------------------------------------------------------------------------
__global__ __launch_bounds__(256) void kP(const float* __restrict__ x,
                                          const float* __restrict__ A_log,
                                          const float* __restrict__ W_B,
                                          const float* __restrict__ Wg,
                                          ushort* __restrict__ wgb,
                                          float* __restrict__ hL,
                                          float* __restrict__ states) {
    __shared__ float wb[D_STATE][D_MODEL + 4];
    __shared__ float bbars[16], abars[16];
    __shared__ float w4[4][16];
    const int tid = threadIdx.x, lane = tid & 63, wave = tid >> 6;

    if (tid < 64) {                       // W_gate cvt slice
        int i = blockIdx.x * 64 + tid;
        const float4* sp = (const float4*)Wg + (size_t)i * 2;
        float4 a = sp[0], b = sp[1];
        float v[8] = {a.x, a.y, a.z, a.w, b.x, b.y, b.z, b.w};
        short8 o;
        #pragma unroll
        for (int j = 0; j < 8; ++j) o[j] = (short)f2bf(v[j]);
        *(short8*)(wgb + (size_t)i * 8) = o;
    }
    if (tid < 16) {
        float A    = -fminf(fmaxf(expf(A_log[tid]), EPSF), 10.0f);
        float Abar = expf(A * DT);
        abars[tid] = Abar;
        bbars[tid] = (fabsf(A) > EPSF) ? (Abar - 1.0f) / (A + EPSF) : DT;
    }
    __syncthreads();
    for (int i = tid; i < D_STATE * D_MODEL; i += 256) {
        int s = i >> 9, m = i & 511;
        wb[s][m] = W_B[i] * bbars[s];
    }
    __syncthreads();

    const int s    = lane & 15;
    const int q    = lane >> 4;                 // 0..3
    const int rloc = q + (wave << 2);           // 0..15
    const int row  = blockIdx.x * 16 + rloc;
    const float* xr = x + (size_t)row * D_MODEL;

    float acc = 0.f;
    #pragma unroll 4
    for (int m = 0; m < D_MODEL; m += 4) {
        float4 xv = *(const float4*)(xr + m);
        float4 wv = *(const float4*)(&wb[s][m]);
        acc += xv.x * wv.x + xv.y * wv.y + xv.z * wv.z + xv.w * wv.w;
    }

    // local scan over rloc for fixed s: within-wave over q (offsets 16,32)
    float abar = abars[s];
    float a = abar, b = acc;
    {
        float ap = __shfl_up(a, 16), bp = __shfl_up(b, 16);
        if (lane >= 16) { b = a * bp + b; a = a * ap; }
    }
    {
        float ap = __shfl_up(a, 32), bp = __shfl_up(b, 32);
        if (lane >= 32) { b = a * bp + b; a = a * ap; }
    }
    if (q == 3) w4[wave][s] = b;                // wave total (a = abar^4 uniform)
    __syncthreads();
    float a4 = abar * abar; a4 = a4 * a4;       // abar^4
    float pb = 0.f;
    for (int w = 0; w < wave; ++w) pb = a4 * pb + w4[w][s];
    float hloc = a * pb + b;                    // inclusive local scan at rloc

    hL[(size_t)row * D_STATE + s] = hloc;
    if (rloc == 15) states[(size_t)blockIdx.x * D_STATE + s] = hloc;
}

// ---------------------------------------------------------------------------
// kc (512 blocks x 256): chunk-prefix combine + h finalize + gate GEMM
// (bf16 MFMA, BK=32, 2 blocks/CU) + h@W_C^T + blend + LayerNorm.
// ---------------------------------------------------------------------------
#define CBM 16
#define BKC 32
__global__ __launch_bounds__(256) void kc_fused(
    const float*  __restrict__ x,      // (8192,512)
    const ushort* __restrict__ Wg,     // bf16 (512,512)
    const float*  __restrict__ hL,     // (8192,16) local-scan values
    const float*  __restrict__ states, // (512,16) chunk end states
    const float*  __restrict__ A_log,
    const float*  __restrict__ W_C,    // (512,16)
    const float*  __restrict__ Dvec,
    const float*  __restrict__ bg,
    const float*  __restrict__ gamma,
    const float*  __restrict__ beta,
    float* __restrict__ out) {
    __shared__ ushort Bsub[512 * BKC];     // 32 KB  (aliased as f32 stg in prologue)
    __shared__ ushort wcs[512 * 16];       // 16 KB
    __shared__ ushort Asub[CBM * BKC];     // 1 KB
    __shared__ ushort hs[CBM * 16];        // 512 B
    __shared__ float  red[4][CBM][2];      // 512 B

    const int tid  = threadIdx.x;
    const int lane = tid & 63, wave = tid >> 6;
    const int r0   = blockIdx.x * CBM;
    const int fr   = lane & 15, kg = lane >> 4;
    const int colw = wave * 128;

    // ---- prologue: stage chunk states (alias Bsub), W_C ----
    float* stg = (float*)Bsub;
    const int c0 = blockIdx.x & 127;               // chunks before ours (this b)
    for (int i = tid; i < c0 * 16; i += 256)
        stg[i] = states[(size_t)(blockIdx.x - c0) * 16 + i];

    #pragma unroll
    for (int it = 0; it < 4; ++it) {
        int idx = it * 256 + tid;                  // row*2 + g
        int row = idx >> 1, g = idx & 1;
        const float4* src = (const float4*)(W_C + (size_t)row * D_STATE + g * 8);
        float4 v0 = src[0], v1 = src[1];
        float v[8] = {v0.x,v0.y,v0.z,v0.w,v1.x,v1.y,v1.z,v1.w};
        short8 o;
        #pragma unroll
        for (int e = 0; e < 8; ++e) o[e] = (short)f2bf(v[e]);
        *(short8*)(wcs + row * 16 + (g ^ (row & 1)) * 8) = o;
    }
    __syncthreads();                               // stg ready

    {   // h finalize: thread (s=tid&15, nloc=tid>>4)
        int s = tid & 15, nloc = tid >> 4;
        float A   = -fminf(fmaxf(expf(A_log[s]), EPSF), 10.0f);
        float a16 = expf(A * DT * 16.0f);
        float p = 0.f;
        for (int cc = 0; cc < c0; ++cc) p = a16 * p + stg[cc * 16 + s];
        float hv = expf(A * DT * (float)(nloc + 1)) * p
                 + hL[(size_t)(r0 + nloc) * D_STATE + s];
        hv = fminf(fmaxf(hv, -10.f), 10.f);
        hs[nloc * 16 + (((s >> 3) ^ (nloc & 1)) * 8) + (s & 7)] = f2bf(hv);
    }

    // ---- gate GEMM: 16 K-steps of BK=32 ----
    floatx4 acc[8] = {};
    const int arow = tid >> 4;
    const int akp  = (tid & 15) * 2;

    for (int kc = 0; kc < D_MODEL; kc += BKC) {
        const float* axp = x + (size_t)(r0 + arow) * D_MODEL + kc + akp;
        float2 av = *(const float2*)axp;

        __syncthreads();               // prior frag-reads / prologue stg-reads done

        {
            int g = akp >> 3;
            int addr = arow * BKC + ((g ^ (arow & 3)) * 8) + (akp & 7);
            ushort2 o; o.x = f2bf(av.x); o.y = f2bf(av.y);
            *(ushort2*)(Asub + addr) = o;
        }
        #pragma unroll
        for (int is = 0; is < 8; ++is) {
            int row = is * 64 + (tid >> 2);
            int g   = (tid & 3) ^ (row & 3);
            const ushort* gsrc = Wg + (size_t)row * D_MODEL + kc + g * 8;
            __builtin_amdgcn_global_load_lds(
                (const __attribute__((address_space(1))) void*)gsrc,
                (__attribute__((address_space(3))) void*)((char*)Bsub + is * 4096 + tid * 16),
                16, 0, 0);
        }
        __syncthreads();               // tile ready

        short8 af = *(const short8*)(Asub + fr * BKC + ((kg ^ (fr & 3)) * 8));
        #pragma unroll
        for (int j = 0; j < 8; ++j) {
            int rb = colw + j * 16 + fr;
            short8 bv = *(const short8*)(Bsub + (size_t)rb * BKC + ((kg ^ (rb & 3)) * 8));
            acc[j] = __builtin_amdgcn_mfma_f32_16x16x32_bf16(af, bv, acc[j], 0, 0, 0);
        }
    }

    // ---- y_ssm = h @ W_C^T (K=32, upper half zero) ----
    const short8 z8 = short8{0,0,0,0,0,0,0,0};
    short8 ah = (kg < 2) ? *(const short8*)(hs + fr * 16 + ((kg ^ (fr & 1)) * 8)) : z8;
    floatx4 yc[8] = {};
    #pragma unroll
    for (int j = 0; j < 8; ++j) {
        int rb = colw + j * 16 + fr;
        short8 bw = (kg < 2) ? *(const short8*)(wcs + rb * 16 + ((kg ^ (rb & 1)) * 8)) : z8;
        yc[j] = __builtin_amdgcn_mfma_f32_16x16x32_bf16(ah, bw, yc[j], 0, 0, 0);
    }

    // ---- epilogue: blend + LN ----
    float vsum[4] = {}, vsq[4] = {};
    #pragma unroll
    for (int j = 0; j < 8; ++j) {
        int col = colw + j * 16 + fr;
        float dv = Dvec[col], bgv = bg[col];
        #pragma unroll
        for (int q = 0; q < 4; ++q) {
            int rl = kg * 4 + q;
            float xv = x[(size_t)(r0 + rl) * D_MODEL + col];
            float lg = acc[j][q] + bgv;
            float gt = 1.f / (1.f + expf(-lg));
            float yv = yc[j][q] + dv * xv;
            float v  = gt * yv + (1.f - gt) * xv;
            acc[j][q] = v;
            vsum[q] += v;
            vsq[q]  += v * v;
        }
    }
    #pragma unroll
    for (int off = 1; off < 16; off <<= 1) {
        #pragma unroll
        for (int q = 0; q < 4; ++q) {
            vsum[q] += __shfl_xor(vsum[q], off);
            vsq[q]  += __shfl_xor(vsq[q], off);
        }
    }
    if (fr == 0) {
        #pragma unroll
        for (int q = 0; q < 4; ++q) {
            red[wave][kg * 4 + q][0] = vsum[q];
            red[wave][kg * 4 + q][1] = vsq[q];
        }
    }
    __syncthreads();
    float mu[4], rs[4];
    #pragma unroll
    for (int q = 0; q < 4; ++q) {
        int rl = kg * 4 + q;
        float s = 0.f, ss = 0.f;
        #pragma unroll
        for (int w = 0; w < 4; ++w) { s += red[w][rl][0]; ss += red[w][rl][1]; }
        float m   = s * (1.f / (float)D_MODEL);
        float var = ss * (1.f / (float)D_MODEL) - m * m;
        mu[q] = m;
        rs[q] = rsqrtf(var + LN_EPSF);
    }
    #pragma unroll
    for (int j = 0; j < 8; ++j) {
        int col = colw + j * 16 + fr;
        float ga = gamma[col], be = beta[col];
        #pragma unroll
        for (int q = 0; q < 4; ++q)
            out[(size_t)(r0 + kg * 4 + q) * D_MODEL + col] =
                (acc[j][q] - mu[q]) * rs[q] * ga + be;
    }
}

// ---------------------------------------------------------------------------
extern "C" void kernel_launch(void* const* d_in, const int* in_sizes, int n_in,
                              void* d_out, int out_size, void* d_ws, size_t ws_size,
                              hipStream_t stream) {
    const float* x     = (const float*)d_in[0];
    const float* A_log = (const float*)d_in[1];
    const float* W_B   = (const float*)d_in[2];
    const float* W_C   = (const float*)d_in[3];
    const float* Dv    = (const float*)d_in[4];
    const float* Wg    = (const float*)d_in[5];
    const float* bg    = (const float*)d_in[6];
    const float* gamma = (const float*)d_in[7];
    const float* beta  = (const float*)d_in[8];
    float* out = (float*)d_out;

    const int rows = NBATCH * NSEQ;                            // 8192

    ushort* wgb    = (ushort*)d_ws;                            // 512 KB
    float*  hL     = (float*)(wgb + (size_t)D_MODEL * D_MODEL);// 512 KB
    float*  states = hL + (size_t)rows * D_STATE;              // 32 KB

    hipLaunchKernelGGL(kP, dim3(rows / 16), dim3(256), 0, stream,
                       x, A_log, W_B, Wg, wgb, hL, states);
    hipLaunchKernelGGL(kc_fused, dim3(rows / CBM), dim3(256), 0, stream,
                       x, wgb, hL, states, A_log, W_C, Dv, bg, gamma, beta, out);
}